// Round 19
// baseline (797.883 us; speedup 1.0000x reference)
//
#include <hip/hip_runtime.h>
#include <cstddef>

#define NN 50000
#define EE 400000
#define BB 64
#define MP 50048            // padded rows: 391 * 128
#define BN_EPS 1e-5f
#define PSEG 32             // pooling segments per graph

typedef __attribute__((ext_vector_type(8))) short s16x8;
typedef __attribute__((ext_vector_type(4))) float f32x4;
typedef __attribute__((ext_vector_type(8))) _Float16 f16x8;

#define GLOAD_LDS16(g, l) __builtin_amdgcn_global_load_lds( \
    (const __attribute__((address_space(1))) void*)(g),     \
    (__attribute__((address_space(3))) void*)(l), 16, 0, 0)

// ---------------- utility ----------------
__global__ void fill_f32(float* __restrict__ p, int n, float v) {
    int i = blockIdx.x * blockDim.x + threadIdx.x;
    if (i < n) p[i] = v;
}

__global__ void fill_i32(int* __restrict__ p, int n, int v) {
    int i = blockIdx.x * blockDim.x + threadIdx.x;
    if (i < n) p[i] = v;
}

__global__ void deg_edges(const int* __restrict__ ei, int* __restrict__ deg) {
    int e = blockIdx.x * blockDim.x + threadIdx.x;
    if (e < EE) atomicAdd(&deg[ei[EE + e]], 1);
}

// all three weight splits in one launch: W [K][N] fp32 -> Wh/Wl [N][K] bf16 planes
__global__ void cvt_wt_all(const float* __restrict__ W0, const float* __restrict__ W1,
                           const float* __restrict__ W2,
                           unsigned short* __restrict__ Wh0, unsigned short* __restrict__ Wl0,
                           unsigned short* __restrict__ Wh1, unsigned short* __restrict__ Wl1,
                           unsigned short* __restrict__ Wh2, unsigned short* __restrict__ Wl2) {
    int i = blockIdx.x * blockDim.x + threadIdx.x;
    const float* W; unsigned short* Wh; unsigned short* Wl; int K, N;
    if (i < 768 * 512)            { W = W0; Wh = Wh0; Wl = Wl0; K = 768; N = 512; }
    else if (i < 768 * 512 + 512 * 256) { i -= 768 * 512; W = W1; Wh = Wh1; Wl = Wl1; K = 512; N = 256; }
    else if (i < 768 * 512 + 512 * 256 + 256 * 128) { i -= 768 * 512 + 512 * 256; W = W2; Wh = Wh2; Wl = Wl2; K = 256; N = 128; }
    else return;
    int k = i / N, n = i % N;
    float f = W[i];
    unsigned int fb = __float_as_uint(f);
    unsigned int hif = fb & 0xFFFF0000u;
    float lo = f - __uint_as_float(hif);
    Wh[(size_t)n * K + k] = (unsigned short)(hif >> 16);
    Wl[(size_t)n * K + k] = (unsigned short)(__float_as_uint(lo) >> 16);
}

// ---------------- CSR build (scan; rsqrt fused) ----------------
__global__ __launch_bounds__(256) void scan_block(const int* __restrict__ deg,
                                                  int* __restrict__ rowptr,
                                                  int* __restrict__ bsum,
                                                  float* __restrict__ dis) {
    __shared__ int tmp[256];
    int tid = threadIdx.x;
    int i = blockIdx.x * 256 + tid;
    int v = (i < NN) ? deg[i] : 0;
    if (i < NN) dis[i] = rsqrtf((float)v + 1.0f);
    tmp[tid] = v;
    __syncthreads();
#pragma unroll
    for (int off = 1; off < 256; off <<= 1) {
        int t = (tid >= off) ? tmp[tid - off] : 0;
        __syncthreads();
        tmp[tid] += t;
        __syncthreads();
    }
    if (i < NN) rowptr[i] = tmp[tid] - v;
    if (tid == 255) bsum[blockIdx.x] = tmp[255];
}

__global__ __launch_bounds__(256) void scan_sums(const int* __restrict__ bsum,
                                                 int* __restrict__ boff, int nb) {
    __shared__ int tmp[256];
    int tid = threadIdx.x;
    int v = (tid < nb) ? bsum[tid] : 0;
    tmp[tid] = v;
    __syncthreads();
#pragma unroll
    for (int off = 1; off < 256; off <<= 1) {
        int t = (tid >= off) ? tmp[tid - off] : 0;
        __syncthreads();
        tmp[tid] += t;
        __syncthreads();
    }
    boff[tid] = tmp[tid] - v;
}

__global__ void scan_fixup(int* __restrict__ rowptr, const int* __restrict__ boff,
                           int* __restrict__ cursor) {
    int i = blockIdx.x * blockDim.x + threadIdx.x;
    if (i < NN) {
        int v = rowptr[i] + boff[i >> 8];
        rowptr[i] = v;
        cursor[i] = v;
    }
    if (i == 0) rowptr[NN] = EE;
}

__global__ void fill_csr(const int* __restrict__ ei, int* __restrict__ cursor,
                         int* __restrict__ csr_src) {
    int e = blockIdx.x * blockDim.x + threadIdx.x;
    if (e >= EE) return;
    int s = ei[e];
    int t = ei[EE + e];
    int pos = atomicAdd(&cursor[t], 1);
    csr_src[pos] = s;
}

// ---------------- split helpers (mask/shift only — hardware-validated r5-r17) ------
// 8 fp32 values -> hi bf16 (truncate) + lo bf16 (truncated residual) planes
static __device__ __forceinline__ void split8(const float* __restrict__ f,
                                              s16x8& h, s16x8& l) {
    unsigned int hi[8], lo[8];
#pragma unroll
    for (int j = 0; j < 8; ++j) {
        unsigned int e = __float_as_uint(f[j]);
        hi[j] = e & 0xFFFF0000u;
        float lf = f[j] - __uint_as_float(hi[j]);
        lo[j] = __float_as_uint(lf);
    }
    union { s16x8 v; unsigned int u[4]; } H, L;
#pragma unroll
    for (int k = 0; k < 4; ++k) {
        H.u[k] = (hi[2 * k + 1]) | (hi[2 * k] >> 16);
        L.u[k] = (lo[2 * k + 1] & 0xFFFF0000u) | (lo[2 * k] >> 16);
    }
    h = H.v; l = L.v;
}

// ------ split-bf16 3-MFMA GEMM, dbuf + XCD swizzle + T2 LDS chunk-XOR-swizzle ------
// C[MP,N] = dis[row] * (A'[MP,K] @ W[N,K]^T), fp16 out. B pre-split bf16 planes.
// AMODE 0: A' = A (fp32 x input). AMODE 2: A' = relu(A*c1[k]+c2[k]) (BN fused).
// r14/r17-validated protocol: STAGE(next) before compute(cur); vmcnt(0)+s_barrier at end.
template <int AMODE>
__global__ __launch_bounds__(256) void gemm_split3(const unsigned int* __restrict__ A,
                                                   const unsigned short* __restrict__ Bh,
                                                   const unsigned short* __restrict__ Bl,
                                                   _Float16* __restrict__ C,
                                                   const float* __restrict__ dis,
                                                   const float* __restrict__ c1p,
                                                   const float* __restrict__ c2p,
                                                   int K, int N) {
    __shared__ unsigned int As[2][128 * 32];     // 2 x 16 KB
    __shared__ unsigned short Bsh[2][128 * 32];  // 2 x 8 KB
    __shared__ unsigned short Bsl[2][128 * 32];  // 2 x 8 KB  (total 64 KB)
    const int tid = threadIdx.x;
    const int w  = tid >> 6;
    const int lw = tid & 63;
    const int lo = lw & 15;
    const int hi = lw >> 4;
    const int wr = w >> 1, wc = w & 1;

    // XCD-aware bijective remap (m204)
    const int nwg = gridDim.x;
    const int q = nwg >> 3, r = nwg & 7;
    int orig = blockIdx.x;
    int xcd = orig & 7, idx = orig >> 3;
    int lid = (xcd < r) ? (xcd * (q + 1) + idx) : (r * (q + 1) + (xcd - r) * q + idx);
    const int nbx = N >> 7;
    const int lbx = (nbx == 4) ? 2 : (nbx == 2 ? 1 : 0);
    const int rowBase = (lid >> lbx) * 128;
    const int colBase = (lid & (nbx - 1)) * 128;

    const int arow = w * 8 + (lw >> 3);
    const int acol = ((lw & 7) ^ (lw >> 3)) * 4;           // pre-swizzled A source chunk
    const int brow = w * 16 + (lw >> 2);
    const int bcol = ((lw & 3) ^ ((lw >> 2) & 3)) * 8;     // pre-swizzled B source chunk

    f32x4 acc[4][4];
#pragma unroll
    for (int m = 0; m < 4; ++m)
#pragma unroll
        for (int n = 0; n < 4; ++n) acc[m][n] = (f32x4){0.f, 0.f, 0.f, 0.f};

#define STAGE(buf, k0s) do {                                                        \
    _Pragma("unroll")                                                               \
    for (int i_ = 0; i_ < 4; ++i_) {                                                \
        int gr_ = rowBase + i_ * 32 + arow;                                         \
        gr_ = (gr_ < NN) ? gr_ : (NN - 1);                                          \
        GLOAD_LDS16(A + (size_t)gr_ * K + (k0s) + acol,                             \
                    (char*)&As[buf][0] + i_ * 4096 + w * 1024);                     \
    }                                                                               \
    _Pragma("unroll")                                                               \
    for (int j_ = 0; j_ < 2; ++j_) {                                                \
        int gc_ = colBase + j_ * 64 + brow;                                         \
        GLOAD_LDS16(Bh + (size_t)gc_ * K + (k0s) + bcol,                            \
                    (char*)&Bsh[buf][0] + j_ * 4096 + w * 1024);                    \
        GLOAD_LDS16(Bl + (size_t)gc_ * K + (k0s) + bcol,                            \
                    (char*)&Bsl[buf][0] + j_ * 4096 + w * 1024);                    \
    }                                                                               \
} while (0)

    STAGE(0, 0);
    asm volatile("s_waitcnt vmcnt(0)" ::: "memory");
    __builtin_amdgcn_s_barrier();

    const int nt = K >> 5;
    int cur = 0;
    for (int t = 0; t < nt; ++t) {
        if (t + 1 < nt) STAGE(cur ^ 1, (t + 1) << 5);   // prefetch next tile (async)

        // per-K-step BN coefs (fragment k-range = k0 + hi*8 .. +7, same for all m)
        float c1v[8], c2v[8];
        if (AMODE == 2) {
            int kb = (t << 5) + hi * 8;
            f32x4 a0 = *(const f32x4*)&c1p[kb];
            f32x4 a1 = *(const f32x4*)&c1p[kb + 4];
            f32x4 b0 = *(const f32x4*)&c2p[kb];
            f32x4 b1 = *(const f32x4*)&c2p[kb + 4];
#pragma unroll
            for (int j = 0; j < 4; ++j) {
                c1v[j] = a0[j]; c1v[4 + j] = a1[j];
                c2v[j] = b0[j]; c2v[4 + j] = b1[j];
            }
        }

        s16x8 ah[4], al[4], bh[4], bl[4];
#pragma unroll
        for (int m = 0; m < 4; ++m) {
            int rr = wr * 64 + m * 16 + lo;
            int c0 = ((hi * 2) ^ (rr & 7)) * 4;
            int c1 = ((hi * 2 + 1) ^ (rr & 7)) * 4;
            uint4 u0 = *(const uint4*)&As[cur][rr * 32 + c0];
            uint4 u1 = *(const uint4*)&As[cur][rr * 32 + c1];
            float f[8];
            f[0] = __uint_as_float(u0.x); f[1] = __uint_as_float(u0.y);
            f[2] = __uint_as_float(u0.z); f[3] = __uint_as_float(u0.w);
            f[4] = __uint_as_float(u1.x); f[5] = __uint_as_float(u1.y);
            f[6] = __uint_as_float(u1.z); f[7] = __uint_as_float(u1.w);
            if (AMODE == 2) {
#pragma unroll
                for (int j = 0; j < 8; ++j)
                    f[j] = fmaxf(f[j] * c1v[j] + c2v[j], 0.f);
            }
            split8(f, ah[m], al[m]);
        }
#pragma unroll
        for (int n = 0; n < 4; ++n) {
            int rr = wc * 64 + n * 16 + lo;
            int cb = (hi ^ (rr & 3)) * 8;
            bh[n] = *(const s16x8*)&Bsh[cur][rr * 32 + cb];
            bl[n] = *(const s16x8*)&Bsl[cur][rr * 32 + cb];
        }
#pragma unroll
        for (int m = 0; m < 4; ++m)
#pragma unroll
            for (int n = 0; n < 4; ++n) {
                acc[m][n] = __builtin_amdgcn_mfma_f32_16x16x32_bf16(ah[m], bh[n], acc[m][n], 0, 0, 0);
                acc[m][n] = __builtin_amdgcn_mfma_f32_16x16x32_bf16(ah[m], bl[n], acc[m][n], 0, 0, 0);
                acc[m][n] = __builtin_amdgcn_mfma_f32_16x16x32_bf16(al[m], bh[n], acc[m][n], 0, 0, 0);
            }

        asm volatile("s_waitcnt vmcnt(0)" ::: "memory");   // next-tile loads landed
        __builtin_amdgcn_s_barrier();                      // all waves done with cur
        cur ^= 1;
    }
#undef STAGE

#pragma unroll
    for (int m = 0; m < 4; ++m) {
        int row0 = rowBase + wr * 64 + m * 16 + hi * 4;
#pragma unroll
        for (int j = 0; j < 4; ++j) {
            int rr = row0 + j;
            float ds = dis[(rr < NN) ? rr : (NN - 1)];
#pragma unroll
            for (int n = 0; n < 4; ++n) {
                int col = colBase + wc * 64 + n * 16 + lo;
                C[(size_t)rr * N + col] = (_Float16)(ds * acc[m][n][j]);
            }
        }
    }
}

// ------ gather aggregation: fp16 hws in, fp32 agg out, 8-deep row-load unroll ------
__global__ __launch_bounds__(256) void agg_gather(const _Float16* __restrict__ hws,
                                                  float* __restrict__ agg,
                                                  const int* __restrict__ rowptr,
                                                  const int* __restrict__ csr_src,
                                                  const float* __restrict__ dis,
                                                  const float* __restrict__ bias,
                                                  int D) {
    const int tpn = D >> 3;
    const int npb = 256 / tpn;
    const int local = threadIdx.x / tpn;
    const int lane = threadIdx.x % tpn;
    const int n = blockIdx.x * npb + local;
    if (n >= NN) return;
    const int dq = lane * 8;
    const _Float16* hb = hws + dq;

    f16x8 sv = *(const f16x8*)&hb[(size_t)n * D];
    float a[8];
#pragma unroll
    for (int j = 0; j < 8; ++j) a[j] = (float)sv[j];

    int e0 = rowptr[n], e1 = rowptr[n + 1];
    int e = e0;
    for (; e + 8 <= e1; e += 8) {
        int s0 = csr_src[e + 0], s1 = csr_src[e + 1];
        int s2 = csr_src[e + 2], s3 = csr_src[e + 3];
        int s4 = csr_src[e + 4], s5 = csr_src[e + 5];
        int s6 = csr_src[e + 6], s7 = csr_src[e + 7];
        f16x8 v0 = *(const f16x8*)&hb[(size_t)s0 * D];
        f16x8 v1 = *(const f16x8*)&hb[(size_t)s1 * D];
        f16x8 v2 = *(const f16x8*)&hb[(size_t)s2 * D];
        f16x8 v3 = *(const f16x8*)&hb[(size_t)s3 * D];
        f16x8 v4 = *(const f16x8*)&hb[(size_t)s4 * D];
        f16x8 v5 = *(const f16x8*)&hb[(size_t)s5 * D];
        f16x8 v6 = *(const f16x8*)&hb[(size_t)s6 * D];
        f16x8 v7 = *(const f16x8*)&hb[(size_t)s7 * D];
#pragma unroll
        for (int j = 0; j < 8; ++j)
            a[j] += (((float)v0[j] + (float)v1[j]) + ((float)v2[j] + (float)v3[j])) +
                    (((float)v4[j] + (float)v5[j]) + ((float)v6[j] + (float)v7[j]));
    }
    for (; e + 4 <= e1; e += 4) {
        int s0 = csr_src[e + 0], s1 = csr_src[e + 1];
        int s2 = csr_src[e + 2], s3 = csr_src[e + 3];
        f16x8 v0 = *(const f16x8*)&hb[(size_t)s0 * D];
        f16x8 v1 = *(const f16x8*)&hb[(size_t)s1 * D];
        f16x8 v2 = *(const f16x8*)&hb[(size_t)s2 * D];
        f16x8 v3 = *(const f16x8*)&hb[(size_t)s3 * D];
#pragma unroll
        for (int j = 0; j < 8; ++j)
            a[j] += ((float)v0[j] + (float)v1[j]) + ((float)v2[j] + (float)v3[j]);
    }
    for (; e < e1; ++e) {
        int s = csr_src[e];
        f16x8 v = *(const f16x8*)&hb[(size_t)s * D];
#pragma unroll
        for (int j = 0; j < 8; ++j) a[j] += (float)v[j];
    }

    float din = dis[n];
    f32x4 o0, o1;
#pragma unroll
    for (int j = 0; j < 4; ++j) o0[j] = din * a[j] + bias[dq + j];
#pragma unroll
    for (int j = 0; j < 4; ++j) o1[j] = din * a[4 + j] + bias[dq + 4 + j];
    *(f32x4*)&agg[(size_t)n * D + dq] = o0;
    *(f32x4*)&agg[(size_t)n * D + dq + 4] = o1;
}

// ---------------- batchnorm stats (vectorized f32x4, 4 ch/thread) ----------------
__global__ __launch_bounds__(64) void bn_stats(const float* __restrict__ h,
                                               float* __restrict__ stats, int D) {
    int quad = blockIdx.x * blockDim.x + threadIdx.x;    // over D/4
    if (quad >= (D >> 2)) return;
    int d = quad * 4;
    f32x4 s = {0.f, 0.f, 0.f, 0.f};
    f32x4 ss = {0.f, 0.f, 0.f, 0.f};
    for (int n = blockIdx.y; n < NN; n += gridDim.y) {
        f32x4 v = *(const f32x4*)&h[(size_t)n * D + d];
        s += v;
        ss += v * v;
    }
#pragma unroll
    for (int j = 0; j < 4; ++j) {
        atomicAdd(&stats[d + j], s[j]);
        atomicAdd(&stats[D + d + j], ss[j]);
    }
}

// ---------------- per-layer BN coefficients: c1 = gamma*rstd, c2 = beta - mean*c1 ---
__global__ void bn_coef(const float* __restrict__ stats,
                        const float* __restrict__ gamma, const float* __restrict__ beta,
                        float* __restrict__ c1, float* __restrict__ c2, int D) {
    int d = blockIdx.x * blockDim.x + threadIdx.x;
    if (d >= D) return;
    float mean = stats[d] * (1.0f / NN);
    float var  = stats[D + d] * (1.0f / NN) - mean * mean;
    float r = rsqrtf(var + BN_EPS) * gamma[d];
    c1[d] = r;
    c2[d] = beta[d] - mean * r;
}

// ---------------- pooling (two-stage segmented, BN affine fused; validated) ------
__global__ void find_starts(const int* __restrict__ batch, int* __restrict__ start) {
    int n = blockIdx.x * blockDim.x + threadIdx.x;
    if (n >= NN) return;
    int bc = batch[n];
    int bp = (n == 0) ? -1 : batch[n - 1];
    for (int g = bp + 1; g <= bc; ++g) start[g] = n;
    if (n == NN - 1) {
        for (int g = bc + 1; g <= BB; ++g) start[g] = NN;
    }
}

__global__ void pool_part(const float* __restrict__ h, const int* __restrict__ start,
                          const float* __restrict__ c1, const float* __restrict__ c2,
                          float* __restrict__ part) {
    int b = blockIdx.x;
    int seg = blockIdx.y;
    int d = threadIdx.x;
    int s0 = start[b], s1 = start[b + 1];
    int len = s1 - s0;
    int a = s0 + (int)((long long)len * seg / PSEG);
    int e = s0 + (int)((long long)len * (seg + 1) / PSEG);
    float a1 = c1[d], a2 = c2[d];
    float sum = 0.f;
    float mx = -3.402823466e+38f;
    for (int n = a; n < e; ++n) {
        float v = a1 * h[(size_t)n * 128 + d] + a2;
        sum += v;
        mx = fmaxf(mx, v);
    }
    part[(size_t)(b * PSEG + seg) * 256 + d] = sum;
    part[(size_t)(b * PSEG + seg) * 256 + 128 + d] = mx;
}

__global__ void pool_reduce(const float* __restrict__ part, const int* __restrict__ start,
                            float* __restrict__ pool) {
    int b = blockIdx.x;
    int d = threadIdx.x;
    float sum = 0.f;
    float mx = -3.402823466e+38f;
    for (int s = 0; s < PSEG; ++s) {
        sum += part[(size_t)(b * PSEG + s) * 256 + d];
        mx = fmaxf(mx, part[(size_t)(b * PSEG + s) * 256 + 128 + d]);
    }
    float cnt = fmaxf((float)(start[b + 1] - start[b]), 1.0f);
    pool[b * 256 + d] = sum / cnt;
    pool[b * 256 + 128 + d] = mx;
}

// ---------------- classifier (single block, fp32) ----------------
__global__ __launch_bounds__(256) void classifier_kernel(
        const float* __restrict__ pool,
        const float* __restrict__ Wc1, const float* __restrict__ bc1,
        const float* __restrict__ gc, const float* __restrict__ bec,
        const float* __restrict__ Wc2, const float* __restrict__ bc2,
        float* __restrict__ out) {
    __shared__ float hc[64][65];
    __shared__ float cmean[64];
    __shared__ float crstd[64];
    int tid = threadIdx.x;

    for (int i = tid; i < 64 * 64; i += 256) {
        int r = i / 64, c = i % 64;
        float acc = bc1[c];
        for (int k = 0; k < 256; ++k)
            acc += pool[r * 256 + k] * Wc1[k * 64 + c];
        hc[r][c] = fmaxf(acc, 0.f);
    }
    __syncthreads();

    if (tid < 64) {
        float s = 0.f, ss = 0.f;
        for (int r = 0; r < 64; ++r) {
            float v = hc[r][tid];
            s += v;
            ss += v * v;
        }
        float m = s * (1.0f / 64.0f);
        float var = ss * (1.0f / 64.0f) - m * m;
        cmean[tid] = m;
        crstd[tid] = rsqrtf(var + BN_EPS);
    }
    __syncthreads();

    if (tid < 128) {
        int r = tid / 2, k = tid % 2;
        float acc = bc2[k];
        for (int c = 0; c < 64; ++c) {
            float v = (hc[r][c] - cmean[c]) * crstd[c] * gc[c] + bec[c];
            acc += v * Wc2[c * 2 + k];
        }
        out[r * 2 + k] = acc;
    }
}

// ---------------- launch ----------------
extern "C" void kernel_launch(void* const* d_in, const int* in_sizes, int n_in,
                              void* d_out, int out_size, void* d_ws, size_t ws_size,
                              hipStream_t stream) {
    const float* x     = (const float*)d_in[0];
    const int*   ei    = (const int*)d_in[1];
    const int*   batch = (const int*)d_in[2];
    const float* W[3]  = {(const float*)d_in[3], (const float*)d_in[7], (const float*)d_in[11]};
    const float* bbv[3] = {(const float*)d_in[4], (const float*)d_in[8], (const float*)d_in[12]};
    const float* gm[3] = {(const float*)d_in[5], (const float*)d_in[9], (const float*)d_in[13]};
    const float* bt[3] = {(const float*)d_in[6], (const float*)d_in[10], (const float*)d_in[14]};
    const float* Wc1 = (const float*)d_in[15];
    const float* bc1 = (const float*)d_in[16];
    const float* gc  = (const float*)d_in[17];
    const float* bec = (const float*)d_in[18];
    const float* Wc2 = (const float*)d_in[19];
    const float* bc2 = (const float*)d_in[20];
    float* out = (float*)d_out;

    // workspace carve-up
    char* p = (char*)d_ws;
    _Float16* hw = (_Float16*)p; p += (size_t)MP * 512 * 2;   // fp16 dis-scaled GEMM out
    float* agg = (float*)p; p += (size_t)NN * 512 * 4;        // agg f32 (gather out / gemm A in)
    unsigned short* Wh[3];
    unsigned short* Wl[3];
    Wh[0] = (unsigned short*)p; p += (size_t)512 * 768 * 2;
    Wl[0] = (unsigned short*)p; p += (size_t)512 * 768 * 2;
    Wh[1] = (unsigned short*)p; p += (size_t)256 * 512 * 2;
    Wl[1] = (unsigned short*)p; p += (size_t)256 * 512 * 2;
    Wh[2] = (unsigned short*)p; p += (size_t)128 * 256 * 2;
    Wl[2] = (unsigned short*)p; p += (size_t)128 * 256 * 2;
    float* dis   = (float*)p; p += (size_t)NN * 4;
    float* stats = (float*)p; p += 1792 * 4;   // per-layer regions: 0 (1024), 1024 (512), 1536 (256)
    float* c1v   = (float*)p; p += 512 * 4;
    float* c2v   = (float*)p; p += 512 * 4;
    float* pool  = (float*)p; p += (size_t)BB * 256 * 4;
    float* part  = (float*)p; p += (size_t)BB * PSEG * 256 * 4;
    int* deg_i   = (int*)p; p += (size_t)NN * 4;
    int* rowptr  = (int*)p; p += (size_t)(NN + 1) * 4;
    int* cursor  = (int*)p; p += (size_t)NN * 4;
    int* bsum    = (int*)p; p += 256 * 4;
    int* boff    = (int*)p; p += 256 * 4;
    int* csr_src = (int*)p; p += (size_t)EE * 4;
    int* start   = (int*)p; p += (BB + 1) * 4;
    const int soff[3] = {0, 1024, 1536};

    const int nb = (NN + 255) / 256;

    // merged weight plane split (1 launch) + upfront stats zero (1 launch)
    cvt_wt_all<<<(768 * 512 + 512 * 256 + 256 * 128 + 255) / 256, 256, 0, stream>>>(
        W[0], W[1], W[2], Wh[0], Wl[0], Wh[1], Wl[1], Wh[2], Wl[2]);
    fill_f32<<<(1792 + 255) / 256, 256, 0, stream>>>(stats, 1792, 0.0f);

    // degree + dis + CSR
    fill_i32<<<nb, 256, 0, stream>>>(deg_i, NN, 0);
    deg_edges<<<(EE + 255) / 256, 256, 0, stream>>>(ei, deg_i);
    scan_block<<<nb, 256, 0, stream>>>(deg_i, rowptr, bsum, dis);
    scan_sums<<<1, 256, 0, stream>>>(bsum, boff, nb);
    scan_fixup<<<nb, 256, 0, stream>>>(rowptr, boff, cursor);
    fill_csr<<<(EE + 255) / 256, 256, 0, stream>>>(ei, cursor, csr_src);

    const int dims[4] = {768, 512, 256, 128};

    for (int l = 0; l < 3; ++l) {
        int K = dims[l], D = dims[l + 1];

        int nwg = (D / 128) * (MP / 128);
        if (l == 0)
            gemm_split3<0><<<nwg, 256, 0, stream>>>((const unsigned int*)x, Wh[0], Wl[0],
                                                    hw, dis, nullptr, nullptr, K, D);
        else
            gemm_split3<2><<<nwg, 256, 0, stream>>>((const unsigned int*)agg, Wh[l], Wl[l],
                                                    hw, dis, c1v, c2v, K, D);

        int tpn = D / 8;
        int npb = 256 / tpn;
        agg_gather<<<(NN + npb - 1) / npb, 256, 0, stream>>>(hw, agg, rowptr, csr_src,
                                                             dis, bbv[l], D);

        dim3 sg((D / 4 + 63) / 64, 256);
        bn_stats<<<sg, 64, 0, stream>>>(agg, stats + soff[l], D);
        bn_coef<<<1, D, 0, stream>>>(stats + soff[l], gm[l], bt[l], c1v, c2v, D);
    }

    find_starts<<<nb, 256, 0, stream>>>(batch, start);
    dim3 pg(BB, PSEG);
    pool_part<<<pg, 128, 0, stream>>>(agg, start, c1v, c2v, part);
    pool_reduce<<<BB, 128, 0, stream>>>(part, start, pool);
    classifier_kernel<<<1, 256, 0, stream>>>(pool, Wc1, bc1, gc, bec, Wc2, bc2, out);
}

// Round 21
// 732.636 us; speedup vs baseline: 1.0891x; 1.0891x over previous
//
#include <hip/hip_runtime.h>
#include <cstddef>

#define NN 50000
#define EE 400000
#define BB 64
#define MP 50048            // padded rows: 391 * 128
#define BN_EPS 1e-5f
#define PSEG 32             // pooling segments per graph

typedef __attribute__((ext_vector_type(8))) short s16x8;
typedef __attribute__((ext_vector_type(4))) float f32x4;
typedef __attribute__((ext_vector_type(8))) _Float16 f16x8;

#define GLOAD_LDS16(g, l) __builtin_amdgcn_global_load_lds( \
    (const __attribute__((address_space(1))) void*)(g),     \
    (__attribute__((address_space(3))) void*)(l), 16, 0, 0)

// ---------------- utility ----------------
__global__ void fill_f32(float* __restrict__ p, int n, float v) {
    int i = blockIdx.x * blockDim.x + threadIdx.x;
    if (i < n) p[i] = v;
}

__global__ void fill_i32(int* __restrict__ p, int n, int v) {
    int i = blockIdx.x * blockDim.x + threadIdx.x;
    if (i < n) p[i] = v;
}

__global__ void deg_edges(const int* __restrict__ ei, int* __restrict__ deg) {
    int e = blockIdx.x * blockDim.x + threadIdx.x;
    if (e < EE) atomicAdd(&deg[ei[EE + e]], 1);
}

// all three weight splits in one launch: W [K][N] fp32 -> Wh/Wl [N][K] bf16 planes
__global__ void cvt_wt_all(const float* __restrict__ W0, const float* __restrict__ W1,
                           const float* __restrict__ W2,
                           unsigned short* __restrict__ Wh0, unsigned short* __restrict__ Wl0,
                           unsigned short* __restrict__ Wh1, unsigned short* __restrict__ Wl1,
                           unsigned short* __restrict__ Wh2, unsigned short* __restrict__ Wl2) {
    int i = blockIdx.x * blockDim.x + threadIdx.x;
    const float* W; unsigned short* Wh; unsigned short* Wl; int K, N;
    if (i < 768 * 512)            { W = W0; Wh = Wh0; Wl = Wl0; K = 768; N = 512; }
    else if (i < 768 * 512 + 512 * 256) { i -= 768 * 512; W = W1; Wh = Wh1; Wl = Wl1; K = 512; N = 256; }
    else if (i < 768 * 512 + 512 * 256 + 256 * 128) { i -= 768 * 512 + 512 * 256; W = W2; Wh = Wh2; Wl = Wl2; K = 256; N = 128; }
    else return;
    int k = i / N, n = i % N;
    float f = W[i];
    unsigned int fb = __float_as_uint(f);
    unsigned int hif = fb & 0xFFFF0000u;
    float lo = f - __uint_as_float(hif);
    Wh[(size_t)n * K + k] = (unsigned short)(hif >> 16);
    Wl[(size_t)n * K + k] = (unsigned short)(__float_as_uint(lo) >> 16);
}

// ---------------- CSR build (scan; rsqrt fused) ----------------
__global__ __launch_bounds__(256) void scan_block(const int* __restrict__ deg,
                                                  int* __restrict__ rowptr,
                                                  int* __restrict__ bsum,
                                                  float* __restrict__ dis) {
    __shared__ int tmp[256];
    int tid = threadIdx.x;
    int i = blockIdx.x * 256 + tid;
    int v = (i < NN) ? deg[i] : 0;
    if (i < NN) dis[i] = rsqrtf((float)v + 1.0f);
    tmp[tid] = v;
    __syncthreads();
#pragma unroll
    for (int off = 1; off < 256; off <<= 1) {
        int t = (tid >= off) ? tmp[tid - off] : 0;
        __syncthreads();
        tmp[tid] += t;
        __syncthreads();
    }
    if (i < NN) rowptr[i] = tmp[tid] - v;
    if (tid == 255) bsum[blockIdx.x] = tmp[255];
}

__global__ __launch_bounds__(256) void scan_sums(const int* __restrict__ bsum,
                                                 int* __restrict__ boff, int nb) {
    __shared__ int tmp[256];
    int tid = threadIdx.x;
    int v = (tid < nb) ? bsum[tid] : 0;
    tmp[tid] = v;
    __syncthreads();
#pragma unroll
    for (int off = 1; off < 256; off <<= 1) {
        int t = (tid >= off) ? tmp[tid - off] : 0;
        __syncthreads();
        tmp[tid] += t;
        __syncthreads();
    }
    boff[tid] = tmp[tid] - v;
}

__global__ void scan_fixup(int* __restrict__ rowptr, const int* __restrict__ boff,
                           int* __restrict__ cursor) {
    int i = blockIdx.x * blockDim.x + threadIdx.x;
    if (i < NN) {
        int v = rowptr[i] + boff[i >> 8];
        rowptr[i] = v;
        cursor[i] = v;
    }
    if (i == 0) rowptr[NN] = EE;
}

__global__ void fill_csr(const int* __restrict__ ei, int* __restrict__ cursor,
                         int* __restrict__ csr_src) {
    int e = blockIdx.x * blockDim.x + threadIdx.x;
    if (e >= EE) return;
    int s = ei[e];
    int t = ei[EE + e];
    int pos = atomicAdd(&cursor[t], 1);
    csr_src[pos] = s;
}

// ---------------- split helpers (mask/shift only — hardware-validated r5-r17) ------
// 8 fp32 values -> hi bf16 (truncate) + lo bf16 (truncated residual) planes
static __device__ __forceinline__ void split8(const float* __restrict__ f,
                                              s16x8& h, s16x8& l) {
    unsigned int hi[8], lo[8];
#pragma unroll
    for (int j = 0; j < 8; ++j) {
        unsigned int e = __float_as_uint(f[j]);
        hi[j] = e & 0xFFFF0000u;
        float lf = f[j] - __uint_as_float(hi[j]);
        lo[j] = __float_as_uint(lf);
    }
    union { s16x8 v; unsigned int u[4]; } H, L;
#pragma unroll
    for (int k = 0; k < 4; ++k) {
        H.u[k] = (hi[2 * k + 1]) | (hi[2 * k] >> 16);
        L.u[k] = (lo[2 * k + 1] & 0xFFFF0000u) | (lo[2 * k] >> 16);
    }
    h = H.v; l = L.v;
}

// ------ split-bf16 3-MFMA GEMM, dbuf + XCD swizzle + T2 LDS chunk-XOR-swizzle ------
// C[MP,N] = dis[row] * (A'[MP,K] @ W[N,K]^T), fp16 out. B pre-split bf16 planes.
// AMODE 0: A' = A (fp32 x input). AMODE 2: A' = relu(A*c1[k]+c2[k]) (BN fused).
// r14/r17-validated protocol: STAGE(next) before compute(cur); vmcnt(0)+s_barrier at end.
template <int AMODE>
__global__ __launch_bounds__(256) void gemm_split3(const unsigned int* __restrict__ A,
                                                   const unsigned short* __restrict__ Bh,
                                                   const unsigned short* __restrict__ Bl,
                                                   _Float16* __restrict__ C,
                                                   const float* __restrict__ dis,
                                                   const float* __restrict__ c1p,
                                                   const float* __restrict__ c2p,
                                                   int K, int N) {
    __shared__ unsigned int As[2][128 * 32];     // 2 x 16 KB
    __shared__ unsigned short Bsh[2][128 * 32];  // 2 x 8 KB
    __shared__ unsigned short Bsl[2][128 * 32];  // 2 x 8 KB  (total 64 KB)
    const int tid = threadIdx.x;
    const int w  = tid >> 6;
    const int lw = tid & 63;
    const int lo = lw & 15;
    const int hi = lw >> 4;
    const int wr = w >> 1, wc = w & 1;

    // XCD-aware bijective remap (m204)
    const int nwg = gridDim.x;
    const int q = nwg >> 3, r = nwg & 7;
    int orig = blockIdx.x;
    int xcd = orig & 7, idx = orig >> 3;
    int lid = (xcd < r) ? (xcd * (q + 1) + idx) : (r * (q + 1) + (xcd - r) * q + idx);
    const int nbx = N >> 7;
    const int lbx = (nbx == 4) ? 2 : (nbx == 2 ? 1 : 0);
    const int rowBase = (lid >> lbx) * 128;
    const int colBase = (lid & (nbx - 1)) * 128;

    const int arow = w * 8 + (lw >> 3);
    const int acol = ((lw & 7) ^ (lw >> 3)) * 4;           // pre-swizzled A source chunk
    const int brow = w * 16 + (lw >> 2);
    const int bcol = ((lw & 3) ^ ((lw >> 2) & 3)) * 8;     // pre-swizzled B source chunk

    f32x4 acc[4][4];
#pragma unroll
    for (int m = 0; m < 4; ++m)
#pragma unroll
        for (int n = 0; n < 4; ++n) acc[m][n] = (f32x4){0.f, 0.f, 0.f, 0.f};

#define STAGE(buf, k0s) do {                                                        \
    _Pragma("unroll")                                                               \
    for (int i_ = 0; i_ < 4; ++i_) {                                                \
        int gr_ = rowBase + i_ * 32 + arow;                                         \
        gr_ = (gr_ < NN) ? gr_ : (NN - 1);                                          \
        GLOAD_LDS16(A + (size_t)gr_ * K + (k0s) + acol,                             \
                    (char*)&As[buf][0] + i_ * 4096 + w * 1024);                     \
    }                                                                               \
    _Pragma("unroll")                                                               \
    for (int j_ = 0; j_ < 2; ++j_) {                                                \
        int gc_ = colBase + j_ * 64 + brow;                                         \
        GLOAD_LDS16(Bh + (size_t)gc_ * K + (k0s) + bcol,                            \
                    (char*)&Bsh[buf][0] + j_ * 4096 + w * 1024);                    \
        GLOAD_LDS16(Bl + (size_t)gc_ * K + (k0s) + bcol,                            \
                    (char*)&Bsl[buf][0] + j_ * 4096 + w * 1024);                    \
    }                                                                               \
} while (0)

    STAGE(0, 0);
    asm volatile("s_waitcnt vmcnt(0)" ::: "memory");
    __builtin_amdgcn_s_barrier();

    const int nt = K >> 5;
    int cur = 0;
    for (int t = 0; t < nt; ++t) {
        if (t + 1 < nt) STAGE(cur ^ 1, (t + 1) << 5);   // prefetch next tile (async)

        // per-K-step BN coefs (fragment k-range = k0 + hi*8 .. +7, same for all m)
        float c1v[8], c2v[8];
        if (AMODE == 2) {
            int kb = (t << 5) + hi * 8;
            f32x4 a0 = *(const f32x4*)&c1p[kb];
            f32x4 a1 = *(const f32x4*)&c1p[kb + 4];
            f32x4 b0 = *(const f32x4*)&c2p[kb];
            f32x4 b1 = *(const f32x4*)&c2p[kb + 4];
#pragma unroll
            for (int j = 0; j < 4; ++j) {
                c1v[j] = a0[j]; c1v[4 + j] = a1[j];
                c2v[j] = b0[j]; c2v[4 + j] = b1[j];
            }
        }

        s16x8 ah[4], al[4], bh[4], bl[4];
#pragma unroll
        for (int m = 0; m < 4; ++m) {
            int rr = wr * 64 + m * 16 + lo;
            int c0 = ((hi * 2) ^ (rr & 7)) * 4;
            int c1 = ((hi * 2 + 1) ^ (rr & 7)) * 4;
            uint4 u0 = *(const uint4*)&As[cur][rr * 32 + c0];
            uint4 u1 = *(const uint4*)&As[cur][rr * 32 + c1];
            float f[8];
            f[0] = __uint_as_float(u0.x); f[1] = __uint_as_float(u0.y);
            f[2] = __uint_as_float(u0.z); f[3] = __uint_as_float(u0.w);
            f[4] = __uint_as_float(u1.x); f[5] = __uint_as_float(u1.y);
            f[6] = __uint_as_float(u1.z); f[7] = __uint_as_float(u1.w);
            if (AMODE == 2) {
#pragma unroll
                for (int j = 0; j < 8; ++j)
                    f[j] = fmaxf(f[j] * c1v[j] + c2v[j], 0.f);
            }
            split8(f, ah[m], al[m]);
        }
#pragma unroll
        for (int n = 0; n < 4; ++n) {
            int rr = wc * 64 + n * 16 + lo;
            int cb = (hi ^ (rr & 3)) * 8;
            bh[n] = *(const s16x8*)&Bsh[cur][rr * 32 + cb];
            bl[n] = *(const s16x8*)&Bsl[cur][rr * 32 + cb];
        }
#pragma unroll
        for (int m = 0; m < 4; ++m)
#pragma unroll
            for (int n = 0; n < 4; ++n) {
                acc[m][n] = __builtin_amdgcn_mfma_f32_16x16x32_bf16(ah[m], bh[n], acc[m][n], 0, 0, 0);
                acc[m][n] = __builtin_amdgcn_mfma_f32_16x16x32_bf16(ah[m], bl[n], acc[m][n], 0, 0, 0);
                acc[m][n] = __builtin_amdgcn_mfma_f32_16x16x32_bf16(al[m], bh[n], acc[m][n], 0, 0, 0);
            }

        asm volatile("s_waitcnt vmcnt(0)" ::: "memory");   // next-tile loads landed
        __builtin_amdgcn_s_barrier();                      // all waves done with cur
        cur ^= 1;
    }
#undef STAGE

#pragma unroll
    for (int m = 0; m < 4; ++m) {
        int row0 = rowBase + wr * 64 + m * 16 + hi * 4;
#pragma unroll
        for (int j = 0; j < 4; ++j) {
            int rr = row0 + j;
            float ds = dis[(rr < NN) ? rr : (NN - 1)];
#pragma unroll
            for (int n = 0; n < 4; ++n) {
                int col = colBase + wc * 64 + n * 16 + lo;
                C[(size_t)rr * N + col] = (_Float16)(ds * acc[m][n][j]);
            }
        }
    }
}

// ------ gather aggregation: fp16 hws in, fp32 agg out, 4-edge unroll (validated) ------
__global__ __launch_bounds__(256) void agg_gather(const _Float16* __restrict__ hws,
                                                  float* __restrict__ agg,
                                                  const int* __restrict__ rowptr,
                                                  const int* __restrict__ csr_src,
                                                  const float* __restrict__ dis,
                                                  const float* __restrict__ bias,
                                                  int D) {
    const int tpn = D >> 3;
    const int npb = 256 / tpn;
    const int local = threadIdx.x / tpn;
    const int lane = threadIdx.x % tpn;
    const int n = blockIdx.x * npb + local;
    if (n >= NN) return;
    const int dq = lane * 8;

    f16x8 sv = *(const f16x8*)&hws[(size_t)n * D + dq];
    float a[8];
#pragma unroll
    for (int j = 0; j < 8; ++j) a[j] = (float)sv[j];

    int e0 = rowptr[n], e1 = rowptr[n + 1];
    int e = e0;
    for (; e + 4 <= e1; e += 4) {
        int s0 = csr_src[e + 0];
        int s1 = csr_src[e + 1];
        int s2 = csr_src[e + 2];
        int s3 = csr_src[e + 3];
        f16x8 v0 = *(const f16x8*)&hws[(size_t)s0 * D + dq];
        f16x8 v1 = *(const f16x8*)&hws[(size_t)s1 * D + dq];
        f16x8 v2 = *(const f16x8*)&hws[(size_t)s2 * D + dq];
        f16x8 v3 = *(const f16x8*)&hws[(size_t)s3 * D + dq];
#pragma unroll
        for (int j = 0; j < 8; ++j)
            a[j] += ((float)v0[j] + (float)v1[j]) + ((float)v2[j] + (float)v3[j]);
    }
    for (; e < e1; ++e) {
        int s = csr_src[e];
        f16x8 v = *(const f16x8*)&hws[(size_t)s * D + dq];
#pragma unroll
        for (int j = 0; j < 8; ++j) a[j] += (float)v[j];
    }

    float din = dis[n];
    f32x4 o0, o1;
#pragma unroll
    for (int j = 0; j < 4; ++j) o0[j] = din * a[j] + bias[dq + j];
#pragma unroll
    for (int j = 0; j < 4; ++j) o1[j] = din * a[4 + j] + bias[dq + 4 + j];
    *(f32x4*)&agg[(size_t)n * D + dq] = o0;
    *(f32x4*)&agg[(size_t)n * D + dq + 4] = o1;
}

// ---------------- batchnorm stats (column-striped, validated) ----------------
__global__ void bn_stats(const float* __restrict__ h, float* __restrict__ stats, int D) {
    int d = blockIdx.x * blockDim.x + threadIdx.x;
    if (d >= D) return;
    float s = 0.f, ss = 0.f;
    for (int n = blockIdx.y; n < NN; n += gridDim.y) {
        float v = h[(size_t)n * D + d];
        s += v;
        ss += v * v;
    }
    atomicAdd(&stats[d], s);
    atomicAdd(&stats[D + d], ss);
}

// ---------------- per-layer BN coefficients: c1 = gamma*rstd, c2 = beta - mean*c1 ---
__global__ void bn_coef(const float* __restrict__ stats,
                        const float* __restrict__ gamma, const float* __restrict__ beta,
                        float* __restrict__ c1, float* __restrict__ c2, int D) {
    int d = blockIdx.x * blockDim.x + threadIdx.x;
    if (d >= D) return;
    float mean = stats[d] * (1.0f / NN);
    float var  = stats[D + d] * (1.0f / NN) - mean * mean;
    float r = rsqrtf(var + BN_EPS) * gamma[d];
    c1[d] = r;
    c2[d] = beta[d] - mean * r;
}

// ---------------- pooling (two-stage segmented, BN affine fused; validated) ------
__global__ void find_starts(const int* __restrict__ batch, int* __restrict__ start) {
    int n = blockIdx.x * blockDim.x + threadIdx.x;
    if (n >= NN) return;
    int bc = batch[n];
    int bp = (n == 0) ? -1 : batch[n - 1];
    for (int g = bp + 1; g <= bc; ++g) start[g] = n;
    if (n == NN - 1) {
        for (int g = bc + 1; g <= BB; ++g) start[g] = NN;
    }
}

__global__ void pool_part(const float* __restrict__ h, const int* __restrict__ start,
                          const float* __restrict__ c1, const float* __restrict__ c2,
                          float* __restrict__ part) {
    int b = blockIdx.x;
    int seg = blockIdx.y;
    int d = threadIdx.x;
    int s0 = start[b], s1 = start[b + 1];
    int len = s1 - s0;
    int a = s0 + (int)((long long)len * seg / PSEG);
    int e = s0 + (int)((long long)len * (seg + 1) / PSEG);
    float a1 = c1[d], a2 = c2[d];
    float sum = 0.f;
    float mx = -3.402823466e+38f;
    for (int n = a; n < e; ++n) {
        float v = a1 * h[(size_t)n * 128 + d] + a2;
        sum += v;
        mx = fmaxf(mx, v);
    }
    part[(size_t)(b * PSEG + seg) * 256 + d] = sum;
    part[(size_t)(b * PSEG + seg) * 256 + 128 + d] = mx;
}

__global__ void pool_reduce(const float* __restrict__ part, const int* __restrict__ start,
                            float* __restrict__ pool) {
    int b = blockIdx.x;
    int d = threadIdx.x;
    float sum = 0.f;
    float mx = -3.402823466e+38f;
    for (int s = 0; s < PSEG; ++s) {
        sum += part[(size_t)(b * PSEG + s) * 256 + d];
        mx = fmaxf(mx, part[(size_t)(b * PSEG + s) * 256 + 128 + d]);
    }
    float cnt = fmaxf((float)(start[b + 1] - start[b]), 1.0f);
    pool[b * 256 + d] = sum / cnt;
    pool[b * 256 + 128 + d] = mx;
}

// ---------------- classifier (single block, fp32) ----------------
__global__ __launch_bounds__(256) void classifier_kernel(
        const float* __restrict__ pool,
        const float* __restrict__ Wc1, const float* __restrict__ bc1,
        const float* __restrict__ gc, const float* __restrict__ bec,
        const float* __restrict__ Wc2, const float* __restrict__ bc2,
        float* __restrict__ out) {
    __shared__ float hc[64][65];
    __shared__ float cmean[64];
    __shared__ float crstd[64];
    int tid = threadIdx.x;

    for (int i = tid; i < 64 * 64; i += 256) {
        int r = i / 64, c = i % 64;
        float acc = bc1[c];
        for (int k = 0; k < 256; ++k)
            acc += pool[r * 256 + k] * Wc1[k * 64 + c];
        hc[r][c] = fmaxf(acc, 0.f);
    }
    __syncthreads();

    if (tid < 64) {
        float s = 0.f, ss = 0.f;
        for (int r = 0; r < 64; ++r) {
            float v = hc[r][tid];
            s += v;
            ss += v * v;
        }
        float m = s * (1.0f / 64.0f);
        float var = ss * (1.0f / 64.0f) - m * m;
        cmean[tid] = m;
        crstd[tid] = rsqrtf(var + BN_EPS);
    }
    __syncthreads();

    if (tid < 128) {
        int r = tid / 2, k = tid % 2;
        float acc = bc2[k];
        for (int c = 0; c < 64; ++c) {
            float v = (hc[r][c] - cmean[c]) * crstd[c] * gc[c] + bec[c];
            acc += v * Wc2[c * 2 + k];
        }
        out[r * 2 + k] = acc;
    }
}

// ---------------- launch ----------------
extern "C" void kernel_launch(void* const* d_in, const int* in_sizes, int n_in,
                              void* d_out, int out_size, void* d_ws, size_t ws_size,
                              hipStream_t stream) {
    const float* x     = (const float*)d_in[0];
    const int*   ei    = (const int*)d_in[1];
    const int*   batch = (const int*)d_in[2];
    const float* W[3]  = {(const float*)d_in[3], (const float*)d_in[7], (const float*)d_in[11]};
    const float* bbv[3] = {(const float*)d_in[4], (const float*)d_in[8], (const float*)d_in[12]};
    const float* gm[3] = {(const float*)d_in[5], (const float*)d_in[9], (const float*)d_in[13]};
    const float* bt[3] = {(const float*)d_in[6], (const float*)d_in[10], (const float*)d_in[14]};
    const float* Wc1 = (const float*)d_in[15];
    const float* bc1 = (const float*)d_in[16];
    const float* gc  = (const float*)d_in[17];
    const float* bec = (const float*)d_in[18];
    const float* Wc2 = (const float*)d_in[19];
    const float* bc2 = (const float*)d_in[20];
    float* out = (float*)d_out;

    // workspace carve-up
    char* p = (char*)d_ws;
    _Float16* hw = (_Float16*)p; p += (size_t)MP * 512 * 2;   // fp16 dis-scaled GEMM out
    float* agg = (float*)p; p += (size_t)NN * 512 * 4;        // agg f32 (gather out / gemm A in)
    unsigned short* Wh[3];
    unsigned short* Wl[3];
    Wh[0] = (unsigned short*)p; p += (size_t)512 * 768 * 2;
    Wl[0] = (unsigned short*)p; p += (size_t)512 * 768 * 2;
    Wh[1] = (unsigned short*)p; p += (size_t)256 * 512 * 2;
    Wl[1] = (unsigned short*)p; p += (size_t)256 * 512 * 2;
    Wh[2] = (unsigned short*)p; p += (size_t)128 * 256 * 2;
    Wl[2] = (unsigned short*)p; p += (size_t)128 * 256 * 2;
    float* dis   = (float*)p; p += (size_t)NN * 4;
    float* stats = (float*)p; p += 1792 * 4;   // per-layer regions: 0 (1024), 1024 (512), 1536 (256)
    float* c1v   = (float*)p; p += 512 * 4;
    float* c2v   = (float*)p; p += 512 * 4;
    float* pool  = (float*)p; p += (size_t)BB * 256 * 4;
    float* part  = (float*)p; p += (size_t)BB * PSEG * 256 * 4;
    int* deg_i   = (int*)p; p += (size_t)NN * 4;
    int* rowptr  = (int*)p; p += (size_t)(NN + 1) * 4;
    int* cursor  = (int*)p; p += (size_t)NN * 4;
    int* bsum    = (int*)p; p += 256 * 4;
    int* boff    = (int*)p; p += 256 * 4;
    int* csr_src = (int*)p; p += (size_t)EE * 4;
    int* start   = (int*)p; p += (BB + 1) * 4;
    const int soff[3] = {0, 1024, 1536};

    const int nb = (NN + 255) / 256;

    // merged weight plane split (1 launch) + upfront stats zero (1 launch)
    cvt_wt_all<<<(768 * 512 + 512 * 256 + 256 * 128 + 255) / 256, 256, 0, stream>>>(
        W[0], W[1], W[2], Wh[0], Wl[0], Wh[1], Wl[1], Wh[2], Wl[2]);
    fill_f32<<<(1792 + 255) / 256, 256, 0, stream>>>(stats, 1792, 0.0f);

    // degree + dis + CSR
    fill_i32<<<nb, 256, 0, stream>>>(deg_i, NN, 0);
    deg_edges<<<(EE + 255) / 256, 256, 0, stream>>>(ei, deg_i);
    scan_block<<<nb, 256, 0, stream>>>(deg_i, rowptr, bsum, dis);
    scan_sums<<<1, 256, 0, stream>>>(bsum, boff, nb);
    scan_fixup<<<nb, 256, 0, stream>>>(rowptr, boff, cursor);
    fill_csr<<<(EE + 255) / 256, 256, 0, stream>>>(ei, cursor, csr_src);

    const int dims[4] = {768, 512, 256, 128};

    for (int l = 0; l < 3; ++l) {
        int K = dims[l], D = dims[l + 1];

        int nwg = (D / 128) * (MP / 128);
        if (l == 0)
            gemm_split3<0><<<nwg, 256, 0, stream>>>((const unsigned int*)x, Wh[0], Wl[0],
                                                    hw, dis, nullptr, nullptr, K, D);
        else
            gemm_split3<2><<<nwg, 256, 0, stream>>>((const unsigned int*)agg, Wh[l], Wl[l],
                                                    hw, dis, c1v, c2v, K, D);

        int tpn = D / 8;
        int npb = 256 / tpn;
        agg_gather<<<(NN + npb - 1) / npb, 256, 0, stream>>>(hw, agg, rowptr, csr_src,
                                                             dis, bbv[l], D);

        bn_stats<<<dim3((D + 255) / 256, 256), 256, 0, stream>>>(agg, stats + soff[l], D);
        bn_coef<<<1, D, 0, stream>>>(stats + soff[l], gm[l], bt[l], c1v, c2v, D);
    }

    find_starts<<<nb, 256, 0, stream>>>(batch, start);
    dim3 pg(BB, PSEG);
    pool_part<<<pg, 128, 0, stream>>>(agg, start, c1v, c2v, part);
    pool_reduce<<<BB, 128, 0, stream>>>(part, start, pool);
    classifier_kernel<<<1, 256, 0, stream>>>(pool, Wc1, bc1, gc, bec, Wc2, bc2, out);
}